// Round 13
// baseline (24.960 us; speedup 1.0000x reference)
//
#include <hip/hip_runtime.h>
#include <hip/hip_fp16.h>

#define B_ 8
#define HI 256
#define WI 256
#define HO 1024
#define WO 1024

#define TLE 64            // output tile 64x64, grid 16x16x8
#define NRS 24            // staged low-res rows/cols
#define SSTR 25           // slice stride (floats)
#define HS 18             // hres row stride (vec4)
#define EW 38             // E1 half-row stride in uints (152 B, 72 halfs + pad)
#define SC (255.0f / 1023.0f)
#define F5L2E 7.2134752f  // 5*log2(e)
#define EXPM5 0.0067379470f
#define GW0 0.27406862f
#define GW1 0.45186276f
#define C02 0.13862944f   // 0.2*ln(2)

__device__ __forceinline__ int basef(int g) {
    int yc = min(max(g, 0), HO - 1);
    return (int)floorf((float)yc * SC) - 2;
}

// Combined conv(gauss3, keys-cubic4) 6-tap. OOB coord -> all-zero weights (so
// the E1 fma chain yields exp2(-F5L2E) = exp(-5) = the zero-pad value).
__device__ __forceinline__ void tap6(int g, int* base_out, float w[6]) {
    int yc = min(max(g, 0), HO - 1);
    int base = basef(g);
#pragma unroll
    for (int s = 0; s < 6; ++s) w[s] = 0.0f;
    if (g >= 0 && g < HO) {
#pragma unroll
        for (int d = -1; d <= 1; ++d) {
            int yd = yc + d;
            if (yd < 0 || yd >= HO) continue;
            float src = (float)yd * SC;
            float fi0 = floorf(src);
            float tt = src - fi0;
            const float a = -0.75f;
            float t1 = tt + 1.0f;
            float c0 = ((a * t1 - 5.0f * a) * t1 + 8.0f * a) * t1 - 4.0f * a;
            float c1 = ((a + 2.0f) * tt - (a + 3.0f)) * tt * tt + 1.0f;
            float u = 1.0f - tt;
            float c2 = ((a + 2.0f) * u - (a + 3.0f)) * u * u + 1.0f;
            float u2 = 2.0f - tt;
            float c3 = ((a * u2 - 5.0f * a) * u2 + 8.0f * a) * u2 - 4.0f * a;
            int s0 = ((int)fi0 - 1) - base;   // in [0,2]
            float gg = (d == 0) ? GW1 : GW0;
            w[s0 + 0] += gg * c0;
            w[s0 + 1] += gg * c1;
            w[s0 + 2] += gg * c2;
            w[s0 + 3] += gg * c3;
        }
    }
    *base_out = base;
}

// pad 6 weights into 8-slot window at shift d (0/1) without dynamic indexing
__device__ __forceinline__ void pad8(const float w[6], int d, float scl, float w8[8]) {
#pragma unroll
    for (int j = 0; j < 8; ++j) {
        float a = (j < 6) ? w[j] : 0.0f;
        float bq = (j >= 1 && j < 7) ? w[j - 1] : 0.0f;
        w8[j] = ((d == 0) ? a : bq) * scl;
    }
}

__device__ __forceinline__ uint4 packw8(const float w8[8]) {
    uint4 r;
    r.x = __builtin_bit_cast(unsigned int, __floats2half2_rn(w8[0], w8[1]));
    r.y = __builtin_bit_cast(unsigned int, __floats2half2_rn(w8[2], w8[3]));
    r.z = __builtin_bit_cast(unsigned int, __floats2half2_rn(w8[4], w8[5]));
    r.w = __builtin_bit_cast(unsigned int, __floats2half2_rn(w8[6], w8[7]));
    return r;
}

__device__ __forceinline__ void unpackw8(uint4 p, float w[8]) {
    __half2 a = __builtin_bit_cast(__half2, p.x);
    __half2 bq = __builtin_bit_cast(__half2, p.y);
    __half2 c = __builtin_bit_cast(__half2, p.z);
    __half2 d = __builtin_bit_cast(__half2, p.w);
    w[0] = __low2float(a);  w[1] = __high2float(a);
    w[2] = __low2float(bq); w[3] = __high2float(bq);
    w[4] = __low2float(c);  w[5] = __high2float(c);
    w[6] = __low2float(d);  w[7] = __high2float(d);
}

__global__ __launch_bounds__(256, 8) void k_fused(const float* __restrict__ in,
                                                  float* __restrict__ out) {
    __shared__ __align__(16) unsigned int Eu[68 * EW];   // E1 half, 10336 B (slice aliases)
    __shared__ float4 Hs[NRS * HS];                      // 6912 B
    __shared__ uint4 xWu[72];                            // 1152 B (8 half weights each)
    __shared__ uint4 vWu[70];                            // 1120 B
    __shared__ int vgb[14], xgb[18];                     // 128 B  -> 19.2 KB total
    float* SL = (float*)Eu;

    const int tid = threadIdx.x;
    const int bx = blockIdx.x, by = blockIdx.y, b = blockIdx.z;
    const int gy0 = by * TLE, gx0 = bx * TLE;
    const int rlo = basef(gy0 - 3);
    const int clo = basef(gx0 - 4);

    // ---- Phase 0: tables + sigmoid'd clamped input slice ----
    if (tid < 70) {                       // vertical weights, fy = tid+1
        int fy = tid + 1;
        int base; float w[6];
        tap6(gy0 + fy - 3, &base, w);
        int q = tid / 5;
        int bs = basef(gy0 + (1 + 5 * q) - 3);
        float w8[8];
        pad8(w, base - bs, F5L2E, w8);
        vWu[tid] = packw8(w8);
    } else if (tid < 84) {
        vgb[tid - 70] = basef(gy0 + (1 + 5 * (tid - 70)) - 3);
    } else if (tid < 102) {
        xgb[tid - 84] = basef(gx0 + 4 * (tid - 84) - 4);
    } else if (tid >= 128 && tid < 200) { // horizontal weights, xe = tid-128
        int xe = tid - 128;
        int base; float w[6];
        tap6(gx0 + xe - 4, &base, w);
        int bs = basef(gx0 + (xe & ~3) - 4);
        float w8[8];
        pad8(w, base - bs, 1.0f, w8);
        xWu[xe] = packw8(w8);
    }
    {
        const float* pin = in + b * (HI * WI);
        int cc = tid & 31, rr0 = tid >> 5;
        if (cc < NRS) {
            for (int rr = rr0; rr < NRS; rr += 8) {
                int row = min(max(rlo + rr, 0), HI - 1);
                int col = min(max(clo + cc, 0), HI - 1);
                float x = pin[row * WI + col];
                SL[rr * SSTR + cc] = 1.0f / (1.0f + __expf(-x));
            }
        }
    }
    __syncthreads();

    const int ty = tid / HS;          // [0,14) for tid < 252
    const int tx = tid - ty * HS;

    // ---- Stage A: horizontal 8-window 6-tap -> Hs[24][18] ----
    if (tid < 252) {
        int cbg = xgb[tx] - clo;
        int wc[8];
#pragma unroll
        for (int j = 0; j < 8; ++j) wc[j] = min(cbg + j, NRS - 1);
        float xw0[8], xw1[8], xw2[8], xw3[8];
        {
            int xe0 = tx << 2;
            unpackw8(xWu[xe0 + 0], xw0);
            unpackw8(xWu[xe0 + 1], xw1);
            unpackw8(xWu[xe0 + 2], xw2);
            unpackw8(xWu[xe0 + 3], xw3);
        }
        for (int r = ty; r < NRS; r += 14) {
            const float* srow = SL + r * SSTR;
            float wnd[8];
#pragma unroll
            for (int j = 0; j < 8; ++j) wnd[j] = srow[wc[j]];
            float s0 = wnd[0]*xw0[0], s1 = wnd[0]*xw1[0], s2 = wnd[0]*xw2[0], s3 = wnd[0]*xw3[0];
#pragma unroll
            for (int j = 1; j < 8; ++j) {
                s0 = fmaf(wnd[j], xw0[j], s0);
                s1 = fmaf(wnd[j], xw1[j], s1);
                s2 = fmaf(wnd[j], xw2[j], s2);
                s3 = fmaf(wnd[j], xw3[j], s3);
            }
            Hs[r * HS + tx] = make_float4(s0, s1, s2, s3);
        }
    }
    __syncthreads();

    // ---- Stage B: vertical 8-row register window -> E1 (half2) rows fy 1..68 ----
    if (tid < 252) {
        const int q = ty;
        const int rbase = vgb[q] - rlo;
        float4 h[8];
#pragma unroll
        for (int i = 0; i < 8; ++i) h[i] = Hs[min(rbase + i, NRS - 1) * HS + tx];
#pragma unroll
        for (int i = 0; i < 5; ++i) {
            int fy = 1 + 5 * q + i;
            if (fy <= 68) {
                float wv[8];
                unpackw8(vWu[fy - 1], wv);
                float ax = -F5L2E, ay = -F5L2E, az = -F5L2E, aw = -F5L2E;
#pragma unroll
                for (int j = 0; j < 8; ++j) {
                    ax = fmaf(wv[j], h[j].x, ax);
                    ay = fmaf(wv[j], h[j].y, ay);
                    az = fmaf(wv[j], h[j].z, az);
                    aw = fmaf(wv[j], h[j].w, aw);
                }
                unsigned int p0 = __builtin_bit_cast(unsigned int, __floats2half2_rn(exp2f(ax), exp2f(ay)));
                unsigned int p1 = __builtin_bit_cast(unsigned int, __floats2half2_rn(exp2f(az), exp2f(aw)));
                *reinterpret_cast<uint2*>(&Eu[(fy - 1) * EW + 2 * tx]) = make_uint2(p0, p1);
            }
        }
    }
    __syncthreads();

    // ---- Stage CD: rolling E2 (min) -> out (log), fp16 E1 reads, 4 rows/thread ----
    {
        const int dx = tid & 15;
        const int sq = tid >> 4;
        const int lr0 = 4 * sq;
        const bool rT = (by == 0)  && (sq == 0);
        const bool rB = (by == 15) && (sq == 15);
        const bool cL = (bx == 0)  && (dx == 0);
        const bool cR = (bx == 15) && (dx == 15);

        // HSUM: E1 half row lr, frame half cols [4dx+2 .. 4dx+9] -> 6 sums
        auto HSUM = [&](int lr, float hs[6]) {
            unsigned int ua = Eu[lr * EW + 2 * dx + 1];                                 // halfs 4dx+2,3
            uint2 ub = *reinterpret_cast<const uint2*>(&Eu[lr * EW + 2 * dx + 2]);      // halfs 4dx+4..7
            unsigned int uc = Eu[lr * EW + 2 * dx + 4];                                 // halfs 4dx+8,9
            __half2 A2 = __builtin_bit_cast(__half2, ua);
            __half2 B2 = __builtin_bit_cast(__half2, ub.x);
            __half2 C2 = __builtin_bit_cast(__half2, ub.y);
            __half2 D2 = __builtin_bit_cast(__half2, uc);
            float e0 = __low2float(A2), e1 = __high2float(A2);
            float e2 = __low2float(B2), e3 = __high2float(B2);
            float e4 = __low2float(C2), e5 = __high2float(C2);
            float e6 = __low2float(D2), e7 = __high2float(D2);
            hs[0] = e0 + e1 + e2;
            hs[1] = e1 + e2 + e3;
            hs[2] = e2 + e3 + e4;
            hs[3] = e3 + e4 + e5;
            hs[4] = e4 + e5 + e6;
            hs[5] = e5 + e6 + e7;
        };
        auto E2F = [&](const float* a, const float* bq, const float* c, bool rowOv) -> float4 {
            float e[6];
#pragma unroll
            for (int j = 0; j < 6; ++j) e[j] = fminf(a[j] + bq[j] + c[j], 1.0f);
            if (rowOv) {
#pragma unroll
                for (int j = 0; j < 6; ++j) e[j] = EXPM5;
            }
            if (cL) e[0] = EXPM5;
            if (cR) e[5] = EXPM5;
            return make_float4(e[0] + e[1] + e[2], e[1] + e[2] + e[3],
                               e[2] + e[3] + e[4], e[3] + e[4] + e[5]);
        };
        auto OUTF = [&](float4 a, float4 bq, float4 c) -> float4 {
            float4 o;
            o.x = fmaxf(fminf(fmaf(C02, __log2f(a.x + bq.x + c.x), 1.0f), 1.0f), 0.0f);
            o.y = fmaxf(fminf(fmaf(C02, __log2f(a.y + bq.y + c.y), 1.0f), 1.0f), 0.0f);
            o.z = fmaxf(fminf(fmaf(C02, __log2f(a.z + bq.z + c.z), 1.0f), 1.0f), 0.0f);
            o.w = fmaxf(fminf(fmaf(C02, __log2f(a.w + bq.w + c.w), 1.0f), 1.0f), 0.0f);
            return o;
        };

        float hA[6], hB[6], hC[6], hD[6];
        size_t obase = ((size_t)(b * HO + by * TLE + 4 * sq) * WO) + bx * TLE + (dx << 2);

        HSUM(lr0 + 0, hA); HSUM(lr0 + 1, hB); HSUM(lr0 + 2, hC);
        float4 eA = E2F(hA, hB, hC, rT);
        HSUM(lr0 + 3, hD); float4 eB = E2F(hB, hC, hD, false);
        HSUM(lr0 + 4, hA); float4 eC = E2F(hC, hD, hA, false);
        *reinterpret_cast<float4*>(out + obase) = OUTF(eA, eB, eC); obase += WO;
        HSUM(lr0 + 5, hB); float4 eD = E2F(hD, hA, hB, false);
        *reinterpret_cast<float4*>(out + obase) = OUTF(eB, eC, eD); obase += WO;
        HSUM(lr0 + 6, hC); float4 eE = E2F(hA, hB, hC, false);
        *reinterpret_cast<float4*>(out + obase) = OUTF(eC, eD, eE); obase += WO;
        HSUM(lr0 + 7, hD); float4 eF = E2F(hB, hC, hD, rB);
        *reinterpret_cast<float4*>(out + obase) = OUTF(eD, eE, eF);
    }
}

extern "C" void kernel_launch(void* const* d_in, const int* in_sizes, int n_in,
                              void* d_out, int out_size, void* d_ws, size_t ws_size,
                              hipStream_t stream) {
    const float* in = (const float*)d_in[0];
    float* out = (float*)d_out;
    dim3 g(WO / TLE, HO / TLE, B_);   // (16,16,8)
    k_fused<<<g, dim3(256), 0, stream>>>(in, out);
}